// Round 3
// baseline (131.088 us; speedup 1.0000x reference)
//
#include <hip/hip_runtime.h>
#include <stdint.h>

#define T_ 256
#define B_ 8
#define E_ 512
#define H_ 32
#define HD_ 16
#define EXP_ 512
#define S_ 768          // T_ + EXP_
#define M_ 2048         // T_ * B_
#define SMOOTH_ 20.0f
#define KSTR 20         // Ks/Qi row stride (bf16): 40B rows -> 2-way (free) b64 reads
#define VSTR 776        // V^T LDS row stride (bf16)
#define OSTR 20         // O-combine LDS row stride (f32)
#define LOG2E_ 1.44269504f
#define MB0_  (-100.988655f)   // -70 * log2e

typedef __attribute__((ext_vector_type(8)))  short bf16x8;
typedef __attribute__((ext_vector_type(4)))  float f32x4;
typedef __attribute__((ext_vector_type(16))) float f32x16;
typedef __attribute__((ext_vector_type(2)))  unsigned int uint32x2;

// single-instruction packed f32->bf16 (RNE), lo = a, hi = b
__device__ __forceinline__ unsigned int cvtpk(float a, float b)
{
    unsigned int r;
    asm("v_cvt_pk_bf16_f32 %0, %1, %2" : "=v"(r) : "v"(a), "v"(b));
    return r;
}
__device__ __forceinline__ ushort bf1(float a)   // RNE scalar
{
    unsigned int u = __float_as_uint(a);
    u = u + 0x7FFFu + ((u >> 16) & 1u);
    return (ushort)(u >> 16);
}

union U16 { uint4 u; bf16x8 v; };
union U8x2 { uint2 p[2]; bf16x8 v; };

// 40B-row loader (stride KSTR=20 bf16): two 8B reads, 2-way banks
__device__ __forceinline__ bf16x8 ld20(const ushort* base, int row, int hi)
{
    U8x2 u;
    const ushort* p = &base[row * KSTR + hi * 8];
    u.p[0] = *(const uint2*)(p);
    u.p[1] = *(const uint2*)(p + 4);
    return u.v;
}

// ---------------------------------------------------------------------------
// Fused QKV-GEMM + attention, v15: VALU-work reduction + latency hiding.
//   - cvt_pk_bf16_f32 (1 op) replaces pku (5 ops) in all staging / P-build
//   - Ks/Qi stride 20 (40B rows): K-read bank conflict 8-way -> 2-way
//   - LAW back to global float4 x4, register-prefetched one iter ahead
//   - next-iter K frag prefetched from LDS; V/msf issued early in-iter
//   - Phase A double-buffered As/Bs: 1 barrier/iter (was 2)
//   - z accumulated in 4 partials (breaks 16-deep serial add chain)
// XCD-aware decode b = bid&7 kept (FETCH 42.7 -> 17.5 MB).
// LDS 87552B: phaseA 2x43776 dbuf | phaseB Ks@0 30720, Vt@30720 24832,
// Qi@55552 10240, msf@65792 3072 (=68864) | epilogue Obuf@0, Zb on msf, Ob=Qi
// ---------------------------------------------------------------------------
__global__ __launch_bounds__(1024, 4)
void qkv_attn_kernel(const float* __restrict__ X,
                     const float* __restrict__ Wq, const float* __restrict__ Wk,
                     const float* __restrict__ Wv,
                     const float* __restrict__ bq, const float* __restrict__ bv,
                     const float* __restrict__ LAW,
                     const int* __restrict__ kpm, const int* __restrict__ em,
                     const int* __restrict__ oc, ushort* __restrict__ Ab)
{
    __shared__ __align__(16) char raw[87552];
    ushort* Ks  = (ushort*)(raw);            // 768*20 bf16   = 30720 B
    ushort* Vt  = (ushort*)(raw + 30720);    // 16*VSTR bf16  = 24832 B
    ushort* Qi  = (ushort*)(raw + 55552);    // 256*20 bf16   = 10240 B
    float*  msf = (float*) (raw + 65792);    // 768 f32       =  3072 B
    float*  Obuf= (float*) (raw);            // post-loop alias: 256*OSTR f32 = 20480 B
    float*  Zb  = (float*) (raw + 65792);    // post-loop alias on msf: 2*256 f32
    ushort* Ob  = Qi;                        // epilogue alias (Qi dead)

    const int bh  = blockIdx.x;
    const int b   = bh & 7;        // XCD-aware: same-b blocks share an XCD L2
    const int h   = bh >> 3;
    const int tid = threadIdx.x;
    const int w   = tid >> 6;      // 0..15
    const int l   = tid & 63;

    // ======================= Phase A: QKV GEMM =======================
    const int r0 = tid >> 3;          // t-row 0..127 (also covers r0+128)
    const int c8 = tid & 7;           // 8-float chunk in the 64-k tile
    const float* Xc0 = &X[((size_t)r0 * 8 + b) * E_ + c8 * 8];
    const float* Xc1 = Xc0 + (size_t)128 * 8 * E_;

    const int wr = tid >> 3;          // valid < 48 (tid < 384)
    const bool wload = (tid < 384);   // wave-uniform (waves 0..5)
    const float* Wsel = (wr < 16) ? Wq : (wr < 32 ? Wk : Wv);
    const float* Wr = &Wsel[((size_t)(h * 16 + (wr & 15))) * E_ + c8 * 8];

    f32x4 acc[3];
#pragma unroll
    for (int m = 0; m < 3; ++m) acc[m] = (f32x4){0.f, 0.f, 0.f, 0.f};

    float4 xa0, xa1, xb0, xb1, wp0, wp1;
    xa0 = *(const float4*)&Xc0[0]; xa1 = *(const float4*)&Xc0[4];
    xb0 = *(const float4*)&Xc1[0]; xb1 = *(const float4*)&Xc1[4];
    if (wload) { wp0 = *(const float4*)&Wr[0]; wp1 = *(const float4*)&Wr[4]; }

    const int ln = l & 15;
    const int lg = l >> 4;

    for (int it = 0; it < 8; ++it) {
        ushort* Ad = (ushort*)(raw + (it & 1) * 43776);
        ushort* Bd = Ad + 18432;
        *(uint4*)&Ad[r0 * 72 + c8 * 8] =
            make_uint4(cvtpk(xa0.x, xa0.y), cvtpk(xa0.z, xa0.w),
                       cvtpk(xa1.x, xa1.y), cvtpk(xa1.z, xa1.w));
        *(uint4*)&Ad[(r0 + 128) * 72 + c8 * 8] =
            make_uint4(cvtpk(xb0.x, xb0.y), cvtpk(xb0.z, xb0.w),
                       cvtpk(xb1.x, xb1.y), cvtpk(xb1.z, xb1.w));
        if (wload)
            *(uint4*)&Bd[wr * 72 + c8 * 8] =
                make_uint4(cvtpk(wp0.x, wp0.y), cvtpk(wp0.z, wp0.w),
                           cvtpk(wp1.x, wp1.y), cvtpk(wp1.z, wp1.w));
        __syncthreads();
        if (it < 7) {
            Xc0 += 64; Xc1 += 64;
            xa0 = *(const float4*)&Xc0[0]; xa1 = *(const float4*)&Xc0[4];
            xb0 = *(const float4*)&Xc1[0]; xb1 = *(const float4*)&Xc1[4];
            if (wload) { Wr += 64; wp0 = *(const float4*)&Wr[0]; wp1 = *(const float4*)&Wr[4]; }
        }
#pragma unroll
        for (int kb = 0; kb < 2; ++kb) {
            bf16x8 af = *(const bf16x8*)&Ad[(w * 16 + ln) * 72 + kb * 32 + lg * 8];
#pragma unroll
            for (int m = 0; m < 3; ++m) {
                bf16x8 bfm = *(const bf16x8*)&Bd[(m * 16 + ln) * 72 + kb * 32 + lg * 8];
                acc[m] = __builtin_amdgcn_mfma_f32_16x16x32_bf16(af, bfm, acc[m], 0, 0, 0);
            }
        }
    }

    __syncthreads();   // buffers dead; image region may be written

    // ---- write Q/K/V images (C-layout: col=ln=d, row=lg*4+r) ----
    {
        const float bqv = bq[h * 16 + ln];
        const float bvv = bv[h * 16 + ln];
#pragma unroll
        for (int r = 0; r < 4; ++r) {
            const int t = w * 16 + lg * 4 + r;
            Qi[t * KSTR + ln] = bf1(acc[0][r] + bqv);
            Ks[t * KSTR + ln] = bf1(acc[1][r]);
            Vt[ln * VSTR + t] = bf1(acc[2][r] + bvv);
        }
    }
    __syncthreads();

    // ---- expansion rows/cols 256..767 (LDS->LDS) + masks ----
    if (tid < 512) {
        const int j   = tid;
        const int src = oc[b * EXP_ + j];
        const ushort* sp = &Ks[src * KSTR];
        ushort* dp = &Ks[(T_ + j) * KSTR];
        uint2 k0 = *(const uint2*)(sp);
        uint2 k1 = *(const uint2*)(sp + 4);
        uint2 k2 = *(const uint2*)(sp + 8);
        uint2 k3 = *(const uint2*)(sp + 12);
        uint2 k4 = *(const uint2*)(sp + 16);
        *(uint2*)(dp)      = k0;
        *(uint2*)(dp + 4)  = k1;
        *(uint2*)(dp + 8)  = k2;
        *(uint2*)(dp + 12) = k3;
        *(uint2*)(dp + 16) = k4;
    } else {
        const int j   = tid - 512;
        const int src = oc[b * EXP_ + j];
#pragma unroll
        for (int d = 0; d < 16; ++d)
            Vt[d * VSTR + T_ + j] = Vt[d * VSTR + src];
    }
    if (tid < 768) {
        const int s = tid;
        const int m = (s < T_) ? kpm[b * T_ + s] : em[b * EXP_ + (s - T_)];
        msf[s] = m ? -1.0e5f : MB0_;
    }
    __syncthreads();

    // ======================= Phase B: attention =======================
    const int slane = l & 31;      // t within the wave's 32-col tile
    const int hi    = l >> 5;
    const int tq    = w & 7;       // t32-tile
    const int sh    = w >> 3;      // s-half
    const int i0    = sh * 12;
    const int iend  = i0 + 12;

    bf16x8 qf = ld20(Qi, tq * 32 + slane, hi);

    const f32x16 zero16 = {0.f,0.f,0.f,0.f,0.f,0.f,0.f,0.f,
                           0.f,0.f,0.f,0.f,0.f,0.f,0.f,0.f};
    f32x16 oacc = zero16;
    float zp0 = 0.f, zp1 = 0.f, zp2 = 0.f, zp3 = 0.f;

    const float* lawb = &LAW[((size_t)b * T_ + tq * 32 + slane) * S_ + 4 * hi];

    // prologue: current-iter K frag + LAW tile in registers
    bf16x8 kf = ld20(Ks, i0 * 32 + slane, hi);
    float4 g0 = *(const float4*)&lawb[i0 * 32];
    float4 g1 = *(const float4*)&lawb[i0 * 32 + 8];
    float4 g2 = *(const float4*)&lawb[i0 * 32 + 16];
    float4 g3 = *(const float4*)&lawb[i0 * 32 + 24];

#pragma unroll 2
    for (int i = i0; i < iend; ++i) {
        const int inx = (i + 1 < iend) ? (i + 1) : i0;   // clamped (dead fetch on last)

        // early issue: V frags + mask row (used later this iter; latency covered)
        bf16x8 vf0 = *(const bf16x8*)&Vt[(l & 15) * VSTR + i * 32 + hi * 8];
        bf16x8 vf1 = *(const bf16x8*)&Vt[(l & 15) * VSTR + i * 32 + 16 + hi * 8];
        const float4 m0 = *(const float4*)&msf[i * 32 + 4 * hi];
        const float4 m1 = *(const float4*)&msf[i * 32 + 8 + 4 * hi];
        const float4 m2 = *(const float4*)&msf[i * 32 + 16 + 4 * hi];
        const float4 m3 = *(const float4*)&msf[i * 32 + 24 + 4 * hi];

        // swapped: A=K (m=s), B=Q (n=t) -> lane holds col t=slane, rows s in regs
        f32x16 sc = __builtin_amdgcn_mfma_f32_32x32x16_bf16(kf, qf, zero16, 0, 0, 0);

        // prefetch next K frag (kf dead after mfma issue)
        bf16x8 kfn = ld20(Ks, inx * 32 + slane, hi);

        const float4 lwg[4] = {g0, g1, g2, g3};
        const float4 mbg[4] = {m0, m1, m2, m3};

#pragma unroll
        for (int ks = 0; ks < 2; ++ks) {
            float pp[8];
#pragma unroll
            for (int gi = 0; gi < 2; ++gi) {
                const int g = 2 * ks + gi;
                const float4 lw4 = lwg[g];
                const float4 mb4 = mbg[g];
                const float lwa[4] = {lw4.x, lw4.y, lw4.z, lw4.w};
                const float mba[4] = {mb4.x, mb4.y, mb4.z, mb4.w};
#pragma unroll
                for (int c = 0; c < 4; ++c) {
                    const float lwv = lwa[c];
                    const float lwK = lwv * LOG2E_;
                    const float arg = __builtin_fmaf(sc[8 * ks + 4 * gi + c], lwK,
                                      __builtin_fmaf(lwK, SMOOTH_, mba[c]));
                    const float e = __builtin_amdgcn_exp2f(arg);
                    if (c == 0) zp0 += e; else if (c == 1) zp1 += e;
                    else if (c == 2) zp2 += e; else zp3 += e;
                    pp[4 * gi + c] = e * lwv;
                }
            }
            // build PV A-frag: words w0..w3, k = hi*8 + j (v14-verified order)
            const unsigned int cA0 = cvtpk(pp[0], pp[1]);
            const unsigned int cA2 = cvtpk(pp[2], pp[3]);
            const unsigned int cB0 = cvtpk(pp[4], pp[5]);
            const unsigned int cB2 = cvtpk(pp[6], pp[7]);
            uint32x2 s0 = __builtin_amdgcn_permlane32_swap(cA0, cB0, false, false);
            uint32x2 s1 = __builtin_amdgcn_permlane32_swap(cA2, cB2, false, false);
            U16 u;
            u.u = make_uint4(s0.x, s1.x, s0.y, s1.y);
            oacc = __builtin_amdgcn_mfma_f32_32x32x16_bf16(
                       u.v, ks ? vf1 : vf0, oacc, 0, 0, 0);
        }

        // prefetch next LAW tile (g* dead after softmax; ~1 iter of latency cover)
        g0 = *(const float4*)&lawb[inx * 32];
        g1 = *(const float4*)&lawb[inx * 32 + 8];
        g2 = *(const float4*)&lawb[inx * 32 + 16];
        g3 = *(const float4*)&lawb[inx * 32 + 24];
        kf = kfn;
    }

    float z = (zp0 + zp1) + (zp2 + zp3);
    z += __shfl_xor(z, 32);

    __syncthreads();   // all waves past the loop: Ks/Vt/msf/Qi dead, alias safe

    if (l < 32) Zb[sh * 256 + tq * 32 + l] = z;

    const int dl = l & 15;
    const bool dok = (l & 31) < 16;   // cols 16..31 of oacc are duplicates
    if (sh == 1 && dok) {
#pragma unroll
        for (int r = 0; r < 16; ++r) {
            const int t = tq * 32 + (r & 3) + 8 * (r >> 2) + 4 * hi;
            Obuf[t * OSTR + dl] = oacc[r];
        }
    }
    __syncthreads();

    if (sh == 0 && dok) {
#pragma unroll
        for (int r = 0; r < 16; ++r) {
            const int t = tq * 32 + (r & 3) + 8 * (r >> 2) + 4 * hi;
            const float Zt  = Zb[t] + Zb[256 + t];
            const float inv = (Zt > 0.f) ? 1.f / Zt : 0.f;
            const float ov  = (oacc[r] + Obuf[t * OSTR + dl]) * inv;
            Ob[t * 16 + dl] = bf1(ov);
        }
    }
    __syncthreads();

    // store to Ab row-major [m][E]: m = t*8+b, cols h*16..h*16+16
    {
        const int t  = tid >> 2;
        const int q4 = tid & 3;
        *(uint2*)&Ab[((size_t)(t * 8 + b)) * E_ + h * 16 + q4 * 4] =
            *(const uint2*)&Ob[t * 16 + q4 * 4];
    }
}

// ---------------------------------------------------------------------------
// out GEMM v3: 32x64 tiles, 512 blocks -> 2 blocks/CU, BK=128 -> 4 K-iters,
// cvt_pk staging. A = Ab bf16 row-major [M][E], B = Wo fp32.
// ---------------------------------------------------------------------------
__global__ __launch_bounds__(256, 2)
void out_gemm(const ushort* __restrict__ Ab, const float* __restrict__ Wo,
              const float* __restrict__ bo, float* __restrict__ dst)
{
    __shared__ __align__(16) ushort sbuf[96 * 136];   // 26112 B
    ushort* As = sbuf;              // 32 rows x 128 k (stride 136)
    ushort* Bs = sbuf + 32 * 136;   // 64 rows x 128 k (stride 136)

    const int n0 = blockIdx.x * 64;
    const int m0 = blockIdx.y * 32;

    const int tid = threadIdx.x;
    const int arow = tid >> 3;          // 0..31
    const int acol = (tid & 7) * 16;    // 0..112
    const int brow = tid >> 2;          // 0..63
    const int bcol = (tid & 3) * 32;    // 0,32,64,96

    const ushort* Ap = &Ab[(size_t)(m0 + arow) * E_ + acol];
    const float*  Wp = &Wo[(size_t)(n0 + brow) * E_ + bcol];

    f32x4 acc[2];
    acc[0] = (f32x4){0.f, 0.f, 0.f, 0.f};
    acc[1] = (f32x4){0.f, 0.f, 0.f, 0.f};

    uint4  ha0 = *(const uint4*)&Ap[0];
    uint4  ha1 = *(const uint4*)&Ap[8];
    float4 f0 = *(const float4*)&Wp[0];
    float4 f1 = *(const float4*)&Wp[4];
    float4 f2 = *(const float4*)&Wp[8];
    float4 f3 = *(const float4*)&Wp[12];
    float4 f4 = *(const float4*)&Wp[16];
    float4 f5 = *(const float4*)&Wp[20];
    float4 f6 = *(const float4*)&Wp[24];
    float4 f7 = *(const float4*)&Wp[28];

    const int l  = tid & 63;
    const int w  = tid >> 6;
    const int wm = w & 1;          // 16-row m half
    const int wn = w >> 1;         // 32-col n half
    const int lq = l >> 4;
    const int ln = l & 15;

    for (int it = 0; it < 4; ++it) {
        __syncthreads();
        *(uint4*)&As[arow * 136 + acol]     = ha0;
        *(uint4*)&As[arow * 136 + acol + 8] = ha1;
        *(uint4*)&Bs[brow * 136 + bcol]      = make_uint4(cvtpk(f0.x, f0.y), cvtpk(f0.z, f0.w),
                                                          cvtpk(f1.x, f1.y), cvtpk(f1.z, f1.w));
        *(uint4*)&Bs[brow * 136 + bcol + 8]  = make_uint4(cvtpk(f2.x, f2.y), cvtpk(f2.z, f2.w),
                                                          cvtpk(f3.x, f3.y), cvtpk(f3.z, f3.w));
        *(uint4*)&Bs[brow * 136 + bcol + 16] = make_uint4(cvtpk(f4.x, f4.y), cvtpk(f4.z, f4.w),
                                                          cvtpk(f5.x, f5.y), cvtpk(f5.z, f5.w));
        *(uint4*)&Bs[brow * 136 + bcol + 24] = make_uint4(cvtpk(f6.x, f6.y), cvtpk(f6.z, f6.w),
                                                          cvtpk(f7.x, f7.y), cvtpk(f7.z, f7.w));
        __syncthreads();
        if (it < 3) {
            Ap += 128; Wp += 128;
            ha0 = *(const uint4*)&Ap[0];
            ha1 = *(const uint4*)&Ap[8];
            f0 = *(const float4*)&Wp[0];
            f1 = *(const float4*)&Wp[4];
            f2 = *(const float4*)&Wp[8];
            f3 = *(const float4*)&Wp[12];
            f4 = *(const float4*)&Wp[16];
            f5 = *(const float4*)&Wp[20];
            f6 = *(const float4*)&Wp[24];
            f7 = *(const float4*)&Wp[28];
        }
#pragma unroll
        for (int kb = 0; kb < 4; ++kb) {
            bf16x8 af  = *(const bf16x8*)&As[(wm * 16 + ln) * 136 + kb * 32 + lq * 8];
            bf16x8 bv0 = *(const bf16x8*)&Bs[(wn * 32 + ln) * 136 + kb * 32 + lq * 8];
            bf16x8 bv1 = *(const bf16x8*)&Bs[(wn * 32 + 16 + ln) * 136 + kb * 32 + lq * 8];
            acc[0] = __builtin_amdgcn_mfma_f32_16x16x32_bf16(af, bv0, acc[0], 0, 0, 0);
            acc[1] = __builtin_amdgcn_mfma_f32_16x16x32_bf16(af, bv1, acc[1], 0, 0, 0);
        }
    }

    const float bo0 = bo[n0 + wn * 32 + ln];
    const float bo1 = bo[n0 + wn * 32 + 16 + ln];

    __syncthreads();
    float* Lf = (float*)sbuf;       // 32 x 68 f32 = 8704 B (aliases As)
#pragma unroll
    for (int j = 0; j < 2; ++j) {
        const float bb = j ? bo1 : bo0;
        const f32x4 a = acc[j];
#pragma unroll
        for (int r = 0; r < 4; ++r)
            Lf[(wm * 16 + lq * 4 + r) * 68 + wn * 32 + j * 16 + ln] = a[r] + bb;
    }
    __syncthreads();

    {
        const int orow = tid >> 3;          // 0..31
        const int oc8  = (tid & 7) * 8;     // 0..56
        float* dp = &dst[(size_t)(m0 + orow) * E_ + n0 + oc8];
        float4 v0 = *(const float4*)&Lf[orow * 68 + oc8];
        float4 v1 = *(const float4*)&Lf[orow * 68 + oc8 + 4];
        *(float4*)&dp[0] = v0;
        *(float4*)&dp[4] = v1;
    }
}

// ---------------------------------------------------------------------------
extern "C" void kernel_launch(void* const* d_in, const int* in_sizes, int n_in,
                              void* d_out, int out_size, void* d_ws, size_t ws_size,
                              hipStream_t stream)
{
    const float* query = (const float*)d_in[0];
    const int*   oc    = (const int*)d_in[1];
    const int*   em    = (const int*)d_in[2];
    const int*   kpm   = (const int*)d_in[3];
    const float* law   = (const float*)d_in[4];
    const float* Wq    = (const float*)d_in[5];
    const float* bq    = (const float*)d_in[6];
    const float* Wk    = (const float*)d_in[7];
    const float* Wv    = (const float*)d_in[8];
    const float* bv    = (const float*)d_in[9];
    const float* Wo    = (const float*)d_in[10];
    const float* bo    = (const float*)d_in[11];
    float* out = (float*)d_out;

    ushort* Ab = (ushort*)d_ws;     // row-major [M][E] bf16

    qkv_attn_kernel<<<B_ * H_, 1024, 0, stream>>>(query, Wq, Wk, Wv, bq, bv,
                                                  law, kpm, em, oc, Ab);

    dim3 go(E_ / 64, M_ / 32, 1);
    out_gemm<<<go, 256, 0, stream>>>(Ab, Wo, bo, out);
}